// Round 14
// baseline (62.717 us; speedup 1.0000x reference)
//
#include <hip/hip_runtime.h>
#include <hip/hip_bf16.h>

// SelfAttention: B=2, S=4096, E=512, D=64, fp32 in/out.
// R14 = R12 (verified, 59.0us) + fragment-packed W:
//  - splitW writes W in the exact per-wave fragment order proj consumes
//    (Wpk[(g*2+ct)*32+kc][lane][8]) -> proj's W loads become coalesced
//    base + lane*16B (R12 had 32-line scattered loads = proj TA storm).
//  - proj phase-2 W addressing updated; all values bit-identical.
// attn/merge verbatim R12 (8-way key-split). No permlane (banned).

typedef float  f32x16 __attribute__((ext_vector_type(16)));
typedef short  v8bf   __attribute__((ext_vector_type(8)));
typedef int    v4i    __attribute__((ext_vector_type(4)));

#define MFMA32(a, b, c) __builtin_amdgcn_mfma_f32_32x32x16_bf16((a), (b), (c), 0, 0, 0)

union Frag { v4i i4; v8bf b8; unsigned u[4]; };

__device__ __forceinline__ unsigned short f2bf(float x) {  // RNE fp32->bf16
    unsigned u = __float_as_uint(x);
    return (unsigned short)((u + 0x7fffu + ((u >> 16) & 1u)) >> 16);
}
__device__ __forceinline__ float bf2f(unsigned short h) {
    return __uint_as_float(((unsigned)h) << 16);
}
__device__ __forceinline__ unsigned cvt_pk_bf16(float a, float b) {
    unsigned r;
    asm("v_cvt_pk_bf16_f32 %0, %1, %2" : "=v"(r) : "v"(a), "v"(b));
    return r;
}

// ---------------- W split -> fragment-packed hi/lo bf16; Wq pre-scaled --------
// Wpk[gg][kc][l][j] = W[g*64+ct*32+(l&31)][kc*16 + 8*(l>>5) + j],  gg = g*2+ct.

__global__ __launch_bounds__(256) void splitW_kernel(
    const float* __restrict__ wq, const float* __restrict__ wk, const float* __restrict__ wv,
    unsigned short* __restrict__ hi, unsigned short* __restrict__ lo)
{
    int i = blockIdx.x * 256 + threadIdx.x;  // exactly 24576 threads
    int e = i * 4;
    const float* src = (e < 32768) ? wq : (e < 65536) ? wk : wv;
    const float sc = (e < 32768) ? 11.541560327111707f : 1.0f;  // 8*log2(e) into Q
    int off = e & 32767;
    float4 v = *reinterpret_cast<const float4*>(src + off);
    v.x *= sc; v.y *= sc; v.z *= sc; v.w *= sc;
    unsigned short h0 = f2bf(v.x), h1 = f2bf(v.y), h2 = f2bf(v.z), h3 = f2bf(v.w);
    unsigned short l0 = f2bf(v.x - bf2f(h0)), l1 = f2bf(v.y - bf2f(h1));
    unsigned short l2 = f2bf(v.z - bf2f(h2)), l3 = f2bf(v.w - bf2f(h3));

    const int r = e >> 9, c = e & 511;
    const int g = r >> 6, rr = r & 63, ct = rr >> 5, r32 = rr & 31;
    const int kc = c >> 4, h = (c >> 3) & 1, j0 = c & 7;
    const int l = h * 32 + r32;
    const int po = ((((g * 2 + ct) * 32 + kc) * 64 + l) * 8 + j0);
    *reinterpret_cast<uint2*>(hi + po) =
        make_uint2((unsigned)h0 | ((unsigned)h1 << 16), (unsigned)h2 | ((unsigned)h3 << 16));
    *reinterpret_cast<uint2*>(lo + po) =
        make_uint2((unsigned)l0 | ((unsigned)l1 << 16), (unsigned)l2 | ((unsigned)l3 << 16));
}

// ---------------- fused projection (R12 + packed-W loads) ----------------

__global__ __launch_bounds__(384, 1) void proj_kernel(
    const float* __restrict__ X,
    const unsigned short* __restrict__ Whi, const unsigned short* __restrict__ Wlo,
    unsigned short* __restrict__ Qhi, unsigned short* __restrict__ Qlo,
    unsigned short* __restrict__ Khi, unsigned short* __restrict__ Klo,
    unsigned short* __restrict__ VT)
{
    __shared__ uint4 XhiS[2048];   // 32 KB
    __shared__ uint4 XloS[2048];   // 32 KB
    __shared__ float t4[4][32][33];

    const int tid = threadIdx.x;
    const int w = tid >> 6;        // 0..5
    const int l = tid & 63, h = l >> 5, r32 = l & 31;
    const int row0 = blockIdx.x * 32;
    const int g = w >> 1, ct = w & 1;

    for (int id = tid; id < 2048; id += 384) {
        const int row = id >> 6, cc = id & 63;
        const float* xp = X + (row0 + row) * 512 + cc * 8;
        float4 va = *reinterpret_cast<const float4*>(xp);
        float4 vb = *reinterpret_cast<const float4*>(xp + 4);
        float xs[8] = {va.x, va.y, va.z, va.w, vb.x, vb.y, vb.z, vb.w};
        unsigned uh[4], ul[4];
#pragma unroll
        for (int j = 0; j < 4; ++j) {
            unsigned short h0 = f2bf(xs[2 * j]),            h1 = f2bf(xs[2 * j + 1]);
            unsigned short l0 = f2bf(xs[2 * j] - bf2f(h0)), l1 = f2bf(xs[2 * j + 1] - bf2f(h1));
            uh[j] = (unsigned)h0 | ((unsigned)h1 << 16);
            ul[j] = (unsigned)l0 | ((unsigned)l1 << 16);
        }
        const int idx = row * 64 + (cc ^ (row & 7));
        XhiS[idx] = make_uint4(uh[0], uh[1], uh[2], uh[3]);
        XloS[idx] = make_uint4(ul[0], ul[1], ul[2], ul[3]);
    }
    __syncthreads();

    f32x16 a0;
#pragma unroll
    for (int r = 0; r < 16; ++r) a0[r] = 0.f;

    const int wgg = (g * 2 + ct) * 32;   // packed-W row group
    for (int kc = 0; kc < 32; ++kc) {
        const int idx = r32 * 64 + ((kc * 2 + h) ^ (r32 & 7));
        const int wbase = ((wgg + kc) * 64 + l) * 8;   // coalesced: lane*16B
        Frag xh, b0h;
        xh.i4 = *reinterpret_cast<const v4i*>(&XhiS[idx]);
        b0h.i4 = *reinterpret_cast<const v4i*>(Whi + wbase);
        a0 = MFMA32(xh.b8, b0h.b8, a0);
        if (g < 2) {
            Frag xl, b0l;
            xl.i4 = *reinterpret_cast<const v4i*>(&XloS[idx]);
            b0l.i4 = *reinterpret_cast<const v4i*>(Wlo + wbase);
            a0 = MFMA32(xh.b8, b0l.b8, a0);
            a0 = MFMA32(xl.b8, b0h.b8, a0);
        }
    }

    const int bb = row0 >> 12;
    const int tl = (row0 & 4095) >> 5;

    if (g < 2) {
#pragma unroll
        for (int u = 0; u < 16; ++u)
            t4[w][(u & 3) + 8 * (u >> 2) + 4 * h][r32] = a0[u];
    }
    __syncthreads();

    if (g == 2) {
#pragma unroll
        for (int c = 0; c < 2; ++c)
#pragma unroll
            for (int hp = 0; hp < 2; ++hp) {
                unsigned p0 = (unsigned)f2bf(a0[8*c + 4*hp + 0]) |
                              ((unsigned)f2bf(a0[8*c + 4*hp + 1]) << 16);
                unsigned p1 = (unsigned)f2bf(a0[8*c + 4*hp + 2]) |
                              ((unsigned)f2bf(a0[8*c + 4*hp + 3]) << 16);
                const int off = ((((bb*128 + tl)*2 + c)*2 + ct)*64 + 32*hp + r32)*8 + 4*h;
                *reinterpret_cast<uint2*>(VT + off) = make_uint2(p0, p1);
            }
    } else if (g == 0) {
        unsigned wh[8], wl[8];
#pragma unroll
        for (int j = 0; j < 8; ++j) {
            float x0 = t4[w][r32][16 * h + 2 * j];
            float x1 = t4[w][r32][16 * h + 2 * j + 1];
            unsigned short h0 = f2bf(x0), h1 = f2bf(x1);
            unsigned short l0 = f2bf(x0 - bf2f(h0)), l1 = f2bf(x1 - bf2f(h1));
            wh[j] = (unsigned)h0 | ((unsigned)h1 << 16);
            wl[j] = (unsigned)l0 | ((unsigned)l1 << 16);
        }
        const int off = (row0 + r32) * 64 + ct * 32 + 16 * h;
        *reinterpret_cast<uint4*>(Qhi + off)     = make_uint4(wh[0], wh[1], wh[2], wh[3]);
        *reinterpret_cast<uint4*>(Qhi + off + 8) = make_uint4(wh[4], wh[5], wh[6], wh[7]);
        *reinterpret_cast<uint4*>(Qlo + off)     = make_uint4(wl[0], wl[1], wl[2], wl[3]);
        *reinterpret_cast<uint4*>(Qlo + off + 8) = make_uint4(wl[4], wl[5], wl[6], wl[7]);
    } else {
        const int dc = ct * 2 + h;
#pragma unroll
        for (int hp = 0; hp < 2; ++hp) {
            unsigned wh[4], wl[4];
#pragma unroll
            for (int jj = 0; jj < 4; ++jj) {
                float x0 = t4[w][r32][16 * h + 8 * hp + 2 * jj];
                float x1 = t4[w][r32][16 * h + 8 * hp + 2 * jj + 1];
                unsigned short h0 = f2bf(x0), h1 = f2bf(x1);
                unsigned short l0 = f2bf(x0 - bf2f(h0)), l1 = f2bf(x1 - bf2f(h1));
                wh[jj] = (unsigned)h0 | ((unsigned)h1 << 16);
                wl[jj] = (unsigned)l0 | ((unsigned)l1 << 16);
            }
            const int off = (((bb*128 + tl)*4 + dc)*64 + 32*hp + r32)*8;
            *reinterpret_cast<uint4*>(Khi + off) = make_uint4(wh[0], wh[1], wh[2], wh[3]);
            *reinterpret_cast<uint4*>(Klo + off) = make_uint4(wl[0], wl[1], wl[2], wl[3]);
        }
    }
}

// ---------------- flash attention (verbatim R12) ----------

__global__ __launch_bounds__(512, 2) void attn_kernel(
    const unsigned short* __restrict__ Qhi, const unsigned short* __restrict__ Qlo,
    const unsigned short* __restrict__ Khi, const unsigned short* __restrict__ Klo,
    const unsigned short* __restrict__ VT,
    float* __restrict__ Opart, float* __restrict__ ml)
{
    __shared__ unsigned short S[2][3][4096];   // 48 KB
    __shared__ float sO[8][32][68];            // 69.6 KB

    const int tid = threadIdx.x;
    const int w = tid >> 6;
    const int l = tid & 63;
    const int h = l >> 5;
    const int q = l & 31;
    const int bx = blockIdx.x;            // 0..31
    const int b  = bx >> 4;
    const int ks = blockIdx.y;            // 0..7 key-split
    const int rowg0 = bx * 256 + w * 32;

    Frag qh[4], ql[4];
#pragma unroll
    for (int dc = 0; dc < 4; ++dc) {
        const int o = (rowg0 + q) * 64 + dc * 16 + 8 * h;
        qh[dc].i4 = *reinterpret_cast<const v4i*>(Qhi + o);
        ql[dc].i4 = *reinterpret_cast<const v4i*>(Qlo + o);
    }

    f32x16 o0, o1;
#pragma unroll
    for (int r = 0; r < 16; ++r) { o0[r] = 0.f; o1[r] = 0.f; }
    float m_run = -1e30f, l_run = 0.f;

    const size_t tb0 = ((size_t)(b * 128 + ks * 16)) * 2048;

    uint4 rg0, rg1, rg2;
    {
        const size_t s = tb0 + (size_t)tid * 8;
        rg0 = *reinterpret_cast<const uint4*>(Khi + s);
        rg1 = *reinterpret_cast<const uint4*>(Klo + s);
        rg2 = *reinterpret_cast<const uint4*>(VT + s);
        *reinterpret_cast<uint4*>(&S[0][0][tid * 8]) = rg0;
        *reinterpret_cast<uint4*>(&S[0][1][tid * 8]) = rg1;
        *reinterpret_cast<uint4*>(&S[0][2][tid * 8]) = rg2;
    }
    __syncthreads();

    for (int it = 0; it < 8; ++it) {
        const int cur = it & 1;
        if (it < 7) {
            const size_t s = tb0 + (size_t)(it + 1) * 4096 + (size_t)tid * 8;
            rg0 = *reinterpret_cast<const uint4*>(Khi + s);
            rg1 = *reinterpret_cast<const uint4*>(Klo + s);
            rg2 = *reinterpret_cast<const uint4*>(VT + s);
        }

        f32x16 sA, sB;
#pragma unroll
        for (int r = 0; r < 16; ++r) { sA[r] = 0.f; sB[r] = 0.f; }
#pragma unroll
        for (int dc = 0; dc < 4; ++dc) {
            Frag kha, kla, khb, klb;
            kha.i4 = *reinterpret_cast<const v4i*>(&S[cur][0][dc * 512 + l * 8]);
            khb.i4 = *reinterpret_cast<const v4i*>(&S[cur][0][2048 + dc * 512 + l * 8]);
            kla.i4 = *reinterpret_cast<const v4i*>(&S[cur][1][dc * 512 + l * 8]);
            klb.i4 = *reinterpret_cast<const v4i*>(&S[cur][1][2048 + dc * 512 + l * 8]);
            sA = MFMA32(kha.b8, qh[dc].b8, sA);
            sB = MFMA32(khb.b8, qh[dc].b8, sB);
            sA = MFMA32(kha.b8, ql[dc].b8, sA);
            sB = MFMA32(khb.b8, ql[dc].b8, sB);
            sA = MFMA32(kla.b8, qh[dc].b8, sA);
            sB = MFMA32(klb.b8, qh[dc].b8, sB);
        }

        float mb;
        {
            float t[8];
#pragma unroll
            for (int jj = 0; jj < 4; ++jj) {
                t[jj]     = fmaxf(fmaxf(sA[4 * jj], sA[4 * jj + 1]),
                                  fmaxf(sA[4 * jj + 2], sA[4 * jj + 3]));
                t[4 + jj] = fmaxf(fmaxf(sB[4 * jj], sB[4 * jj + 1]),
                                  fmaxf(sB[4 * jj + 2], sB[4 * jj + 3]));
            }
            float u0 = fmaxf(fmaxf(t[0], t[1]), fmaxf(t[2], t[3]));
            float u1 = fmaxf(fmaxf(t[4], t[5]), fmaxf(t[6], t[7]));
            mb = fmaxf(u0, u1);
        }
        mb = fmaxf(mb, __shfl_xor(mb, 32));

        if (!__all(mb <= m_run + 8.f)) {
            const float m_new = fmaxf(m_run, mb);
            const float f = exp2f(m_run - m_new);
#pragma unroll
            for (int r = 0; r < 16; ++r) { o0[r] *= f; o1[r] *= f; }
            l_run *= f;
            m_run = m_new;
        }

        float p[32];
        float ps0 = 0.f, ps1 = 0.f, ps2 = 0.f, ps3 = 0.f;
#pragma unroll
        for (int r = 0; r < 16; r += 4) {
            p[r]      = exp2f(sA[r]     - m_run); ps0 += p[r];
            p[r + 1]  = exp2f(sA[r + 1] - m_run); ps1 += p[r + 1];
            p[r + 2]  = exp2f(sA[r + 2] - m_run); ps2 += p[r + 2];
            p[r + 3]  = exp2f(sA[r + 3] - m_run); ps3 += p[r + 3];
            p[16 + r]     = exp2f(sB[r]     - m_run); ps0 += p[16 + r];
            p[16 + r + 1] = exp2f(sB[r + 1] - m_run); ps1 += p[16 + r + 1];
            p[16 + r + 2] = exp2f(sB[r + 2] - m_run); ps2 += p[16 + r + 2];
            p[16 + r + 3] = exp2f(sB[r + 3] - m_run); ps3 += p[16 + r + 3];
        }
        float ps = (ps0 + ps1) + (ps2 + ps3);
        ps += __shfl_xor(ps, 32);
        l_run += ps;

        unsigned U[16];
#pragma unroll
        for (int j = 0; j < 8; ++j) {
            U[j]     = cvt_pk_bf16(p[2 * j],      p[2 * j + 1]);
            U[8 + j] = cvt_pk_bf16(p[16 + 2 * j], p[16 + 2 * j + 1]);
        }
        unsigned tA0 = h ? U[0]  : U[2];
        unsigned tA1 = h ? U[1]  : U[3];
        unsigned tA2 = h ? U[4]  : U[6];
        unsigned tA3 = h ? U[5]  : U[7];
        unsigned tB0 = h ? U[8]  : U[10];
        unsigned tB1 = h ? U[9]  : U[11];
        unsigned tB2 = h ? U[12] : U[14];
        unsigned tB3 = h ? U[13] : U[15];
        unsigned rA0 = __shfl_xor(tA0, 32);
        unsigned rA1 = __shfl_xor(tA1, 32);
        unsigned rA2 = __shfl_xor(tA2, 32);
        unsigned rA3 = __shfl_xor(tA3, 32);
        unsigned rB0 = __shfl_xor(tB0, 32);
        unsigned rB1 = __shfl_xor(tB1, 32);
        unsigned rB2 = __shfl_xor(tB2, 32);
        unsigned rB3 = __shfl_xor(tB3, 32);
        Frag p0f, p1f, p2f, p3f;
        if (h == 0) {
            p0f.u[0] = U[0];  p0f.u[1] = U[1];  p0f.u[2] = rA0;   p0f.u[3] = rA1;
            p1f.u[0] = U[4];  p1f.u[1] = U[5];  p1f.u[2] = rA2;   p1f.u[3] = rA3;
            p2f.u[0] = U[8];  p2f.u[1] = U[9];  p2f.u[2] = rB0;   p2f.u[3] = rB1;
            p3f.u[0] = U[12]; p3f.u[1] = U[13]; p3f.u[2] = rB2;   p3f.u[3] = rB3;
        } else {
            p0f.u[0] = rA0;   p0f.u[1] = rA1;   p0f.u[2] = U[2];  p0f.u[3] = U[3];
            p1f.u[0] = rA2;   p1f.u[1] = rA3;   p1f.u[2] = U[6];  p1f.u[3] = U[7];
            p2f.u[0] = rB0;   p2f.u[1] = rB1;   p2f.u[2] = U[10]; p2f.u[3] = U[11];
            p3f.u[0] = rB2;   p3f.u[1] = rB3;   p3f.u[2] = U[14]; p3f.u[3] = U[15];
        }

#pragma unroll
        for (int tb = 0; tb < 2; ++tb) {
#pragma unroll
            for (int c = 0; c < 2; ++c) {
                const Frag& pf = tb ? (c ? p3f : p2f) : (c ? p1f : p0f);
#pragma unroll
                for (int vc = 0; vc < 2; ++vc) {
                    Frag vf;
                    vf.i4 = *reinterpret_cast<const v4i*>(
                        &S[cur][2][tb * 2048 + (c * 2 + vc) * 512 + l * 8]);
                    if (vc == 0) o0 = MFMA32(vf.b8, pf.b8, o0);
                    else         o1 = MFMA32(vf.b8, pf.b8, o1);
                }
            }
        }

        if (it < 7) {
            const int nxt = cur ^ 1;
            *reinterpret_cast<uint4*>(&S[nxt][0][tid * 8]) = rg0;
            *reinterpret_cast<uint4*>(&S[nxt][1][tid * 8]) = rg1;
            *reinterpret_cast<uint4*>(&S[nxt][2][tid * 8]) = rg2;
        }
        __syncthreads();
    }

    if (h == 0) {
        const int rowg = rowg0 + q;
        *reinterpret_cast<float2*>(&ml[((size_t)ks * 8192 + rowg) * 2]) =
            make_float2(m_run, l_run);
    }
#pragma unroll
    for (int vc = 0; vc < 2; ++vc) {
        const f32x16& a = vc ? o1 : o0;
#pragma unroll
        for (int u = 0; u < 4; ++u) {
            float4 v4 = make_float4(a[4 * u], a[4 * u + 1], a[4 * u + 2], a[4 * u + 3]);
            *reinterpret_cast<float4*>(&sO[w][q][vc * 32 + 8 * u + 4 * h]) = v4;
        }
    }
    __syncthreads();

#pragma unroll
    for (int k = 0; k < 8; ++k) {
        const int f = tid + k * 512;          // 4096 float4 slots
        const int rl = f >> 4;                // local row 0..255
        const int v4 = f & 15;
        float4 val = *reinterpret_cast<const float4*>(&sO[rl >> 5][rl & 31][v4 * 4]);
        *reinterpret_cast<float4*>(
            &Opart[(((size_t)ks * 8192) + bx * 256 + rl) * 64 + v4 * 4]) = val;
    }
}

// ---------------- 8-way cross-split merge (verbatim R12) ----------------
__global__ __launch_bounds__(256) void merge_kernel(
    const float* __restrict__ Opart, const float* __restrict__ ml, float* __restrict__ out)
{
    const int idx = blockIdx.x * 256 + threadIdx.x;  // 131072
    const int row = idx >> 4, vb = (idx & 15) * 4;
    float mv[8], lv[8];
    float ms = -1e30f;
#pragma unroll
    for (int s = 0; s < 8; ++s) {
        float2 m2 = *reinterpret_cast<const float2*>(&ml[((size_t)s * 8192 + row) * 2]);
        mv[s] = m2.x; lv[s] = m2.y;
        ms = fmaxf(ms, m2.x);
    }
    float L = 0.f;
    float a0 = 0.f, a1 = 0.f, a2 = 0.f, a3 = 0.f;
#pragma unroll
    for (int s = 0; s < 8; ++s) {
        const float fw = exp2f(mv[s] - ms);
        L += fw * lv[s];
        float4 a = *reinterpret_cast<const float4*>(
            &Opart[((size_t)s * 8192 + row) * 64 + vb]);
        a0 += fw * a.x; a1 += fw * a.y; a2 += fw * a.z; a3 += fw * a.w;
    }
    const float inv = 1.0f / L;
    *reinterpret_cast<float4*>(out + (size_t)row * 64 + vb) =
        make_float4(a0 * inv, a1 * inv, a2 * inv, a3 * inv);
}

// ---------------- launch ----------------

extern "C" void kernel_launch(void* const* d_in, const int* in_sizes, int n_in,
                              void* d_out, int out_size, void* d_ws, size_t ws_size,
                              hipStream_t stream)
{
    const float* X  = (const float*)d_in[0];
    const float* Wq = (const float*)d_in[1];
    const float* Wk = (const float*)d_in[2];
    const float* Wv = (const float*)d_in[3];
    float* out = (float*)d_out;

    // workspace: QKV-packed buffers first; W (proj-time only, packed) at the
    // tail, aliased by Opart/ml (written only by attn/merge). ~21.5 MiB.
    unsigned short* Qhi = (unsigned short*)d_ws;
    unsigned short* Qlo = Qhi + 524288;    // 8192*64
    unsigned short* Khi = Qlo + 524288;    // Kpk hi: [2][128][4][64][8]
    unsigned short* Klo = Khi + 524288;    // Kpk lo
    unsigned short* VT  = Klo + 524288;    // Vpk: [2][128][2][2][64][8]
    unsigned short* Whi = VT + 524288;     // Wpk hi: [6][32][64][8]
    unsigned short* Wlo = Whi + 98304;     // Wpk lo
    float* Opart = (float*)Whi;            // [8][8192][64] fp32 (aliases W)
    float* ml    = Opart + 4194304;        // [8][8192][2]

    splitW_kernel<<<96, 256, 0, stream>>>(Wq, Wk, Wv, Whi, Wlo);
    proj_kernel<<<256, 384, 0, stream>>>(X, Whi, Wlo, Qhi, Qlo, Khi, Klo, VT);
    attn_kernel<<<dim3(32, 8), 512, 0, stream>>>(Qhi, Qlo, Khi, Klo, VT, Opart, ml);
    merge_kernel<<<512, 256, 0, stream>>>(Opart, ml, out);
}

// Round 15
// 58.316 us; speedup vs baseline: 1.0755x; 1.0755x over previous
//
#include <hip/hip_runtime.h>
#include <hip/hip_bf16.h>

// SelfAttention: B=2, S=4096, E=512, D=64, fp32 in/out.
// R15 = R12 (verified 59.0us; splitW/proj/merge verbatim) + attn occupancy:
// 4-wave blocks (128 queries), grid (64, 8) = 512 blocks -> 2-3 blocks/CU,
// with the sO epilogue buffer aliased over the dead S staging LDS (48 KB).
// Per-CU totals (TA loads, LDS traffic, MFMA, HBM) are identical to R12 —
// only latency overlap improves. No permlane (banned).

typedef float  f32x16 __attribute__((ext_vector_type(16)));
typedef short  v8bf   __attribute__((ext_vector_type(8)));
typedef int    v4i    __attribute__((ext_vector_type(4)));

#define MFMA32(a, b, c) __builtin_amdgcn_mfma_f32_32x32x16_bf16((a), (b), (c), 0, 0, 0)

union Frag { v4i i4; v8bf b8; unsigned u[4]; };

__device__ __forceinline__ unsigned short f2bf(float x) {  // RNE fp32->bf16
    unsigned u = __float_as_uint(x);
    return (unsigned short)((u + 0x7fffu + ((u >> 16) & 1u)) >> 16);
}
__device__ __forceinline__ float bf2f(unsigned short h) {
    return __uint_as_float(((unsigned)h) << 16);
}
__device__ __forceinline__ unsigned cvt_pk_bf16(float a, float b) {
    unsigned r;
    asm("v_cvt_pk_bf16_f32 %0, %1, %2" : "=v"(r) : "v"(a), "v"(b));
    return r;
}

// ---------------- W split: [Wq;Wk;Wv] -> hi/lo bf16; Wq pre-scaled (R12) ------

__global__ __launch_bounds__(256) void splitW_kernel(
    const float* __restrict__ wq, const float* __restrict__ wk, const float* __restrict__ wv,
    unsigned short* __restrict__ hi, unsigned short* __restrict__ lo)
{
    int i = blockIdx.x * 256 + threadIdx.x;  // exactly 24576 threads
    int e = i * 4;
    const float* src = (e < 32768) ? wq : (e < 65536) ? wk : wv;
    const float sc = (e < 32768) ? 11.541560327111707f : 1.0f;  // 8*log2(e) into Q
    int off = e & 32767;
    float4 v = *reinterpret_cast<const float4*>(src + off);
    v.x *= sc; v.y *= sc; v.z *= sc; v.w *= sc;
    unsigned short h0 = f2bf(v.x), h1 = f2bf(v.y), h2 = f2bf(v.z), h3 = f2bf(v.w);
    unsigned short l0 = f2bf(v.x - bf2f(h0)), l1 = f2bf(v.y - bf2f(h1));
    unsigned short l2 = f2bf(v.z - bf2f(h2)), l3 = f2bf(v.w - bf2f(h3));
    reinterpret_cast<uint2*>(hi)[i] =
        make_uint2((unsigned)h0 | ((unsigned)h1 << 16), (unsigned)h2 | ((unsigned)h3 << 16));
    reinterpret_cast<uint2*>(lo)[i] =
        make_uint2((unsigned)l0 | ((unsigned)l1 << 16), (unsigned)l2 | ((unsigned)l3 << 16));
}

// ---------------- fused projection (verbatim R12) ----------------

__global__ __launch_bounds__(384, 1) void proj_kernel(
    const float* __restrict__ X,
    const unsigned short* __restrict__ Whi, const unsigned short* __restrict__ Wlo,
    unsigned short* __restrict__ Qhi, unsigned short* __restrict__ Qlo,
    unsigned short* __restrict__ Khi, unsigned short* __restrict__ Klo,
    unsigned short* __restrict__ VT)
{
    __shared__ uint4 XhiS[2048];   // 32 KB
    __shared__ uint4 XloS[2048];   // 32 KB
    __shared__ float t4[4][32][33];

    const int tid = threadIdx.x;
    const int w = tid >> 6;        // 0..5
    const int l = tid & 63, h = l >> 5, r32 = l & 31;
    const int row0 = blockIdx.x * 32;
    const int g = w >> 1, ct = w & 1;

    for (int id = tid; id < 2048; id += 384) {
        const int row = id >> 6, cc = id & 63;
        const float* xp = X + (row0 + row) * 512 + cc * 8;
        float4 va = *reinterpret_cast<const float4*>(xp);
        float4 vb = *reinterpret_cast<const float4*>(xp + 4);
        float xs[8] = {va.x, va.y, va.z, va.w, vb.x, vb.y, vb.z, vb.w};
        unsigned uh[4], ul[4];
#pragma unroll
        for (int j = 0; j < 4; ++j) {
            unsigned short h0 = f2bf(xs[2 * j]),            h1 = f2bf(xs[2 * j + 1]);
            unsigned short l0 = f2bf(xs[2 * j] - bf2f(h0)), l1 = f2bf(xs[2 * j + 1] - bf2f(h1));
            uh[j] = (unsigned)h0 | ((unsigned)h1 << 16);
            ul[j] = (unsigned)l0 | ((unsigned)l1 << 16);
        }
        const int idx = row * 64 + (cc ^ (row & 7));
        XhiS[idx] = make_uint4(uh[0], uh[1], uh[2], uh[3]);
        XloS[idx] = make_uint4(ul[0], ul[1], ul[2], ul[3]);
    }
    __syncthreads();

    f32x16 a0;
#pragma unroll
    for (int r = 0; r < 16; ++r) a0[r] = 0.f;

    for (int kc = 0; kc < 32; ++kc) {
        const int k0 = kc * 16 + 8 * h;
        const int idx = r32 * 64 + ((kc * 2 + h) ^ (r32 & 7));
        Frag xh, b0h;
        xh.i4 = *reinterpret_cast<const v4i*>(&XhiS[idx]);
        const int w0 = (g * 64 + ct * 32 + r32) * 512 + k0;
        b0h.i4 = *reinterpret_cast<const v4i*>(Whi + w0);
        a0 = MFMA32(xh.b8, b0h.b8, a0);
        if (g < 2) {
            Frag xl, b0l;
            xl.i4 = *reinterpret_cast<const v4i*>(&XloS[idx]);
            b0l.i4 = *reinterpret_cast<const v4i*>(Wlo + w0);
            a0 = MFMA32(xh.b8, b0l.b8, a0);
            a0 = MFMA32(xl.b8, b0h.b8, a0);
        }
    }

    const int bb = row0 >> 12;
    const int tl = (row0 & 4095) >> 5;

    if (g < 2) {
#pragma unroll
        for (int u = 0; u < 16; ++u)
            t4[w][(u & 3) + 8 * (u >> 2) + 4 * h][r32] = a0[u];
    }
    __syncthreads();

    if (g == 2) {
#pragma unroll
        for (int c = 0; c < 2; ++c)
#pragma unroll
            for (int hp = 0; hp < 2; ++hp) {
                unsigned p0 = (unsigned)f2bf(a0[8*c + 4*hp + 0]) |
                              ((unsigned)f2bf(a0[8*c + 4*hp + 1]) << 16);
                unsigned p1 = (unsigned)f2bf(a0[8*c + 4*hp + 2]) |
                              ((unsigned)f2bf(a0[8*c + 4*hp + 3]) << 16);
                const int off = ((((bb*128 + tl)*2 + c)*2 + ct)*64 + 32*hp + r32)*8 + 4*h;
                *reinterpret_cast<uint2*>(VT + off) = make_uint2(p0, p1);
            }
    } else if (g == 0) {
        unsigned wh[8], wl[8];
#pragma unroll
        for (int j = 0; j < 8; ++j) {
            float x0 = t4[w][r32][16 * h + 2 * j];
            float x1 = t4[w][r32][16 * h + 2 * j + 1];
            unsigned short h0 = f2bf(x0), h1 = f2bf(x1);
            unsigned short l0 = f2bf(x0 - bf2f(h0)), l1 = f2bf(x1 - bf2f(h1));
            wh[j] = (unsigned)h0 | ((unsigned)h1 << 16);
            wl[j] = (unsigned)l0 | ((unsigned)l1 << 16);
        }
        const int off = (row0 + r32) * 64 + ct * 32 + 16 * h;
        *reinterpret_cast<uint4*>(Qhi + off)     = make_uint4(wh[0], wh[1], wh[2], wh[3]);
        *reinterpret_cast<uint4*>(Qhi + off + 8) = make_uint4(wh[4], wh[5], wh[6], wh[7]);
        *reinterpret_cast<uint4*>(Qlo + off)     = make_uint4(wl[0], wl[1], wl[2], wl[3]);
        *reinterpret_cast<uint4*>(Qlo + off + 8) = make_uint4(wl[4], wl[5], wl[6], wl[7]);
    } else {
        const int dc = ct * 2 + h;
#pragma unroll
        for (int hp = 0; hp < 2; ++hp) {
            unsigned wh[4], wl[4];
#pragma unroll
            for (int jj = 0; jj < 4; ++jj) {
                float x0 = t4[w][r32][16 * h + 8 * hp + 2 * jj];
                float x1 = t4[w][r32][16 * h + 8 * hp + 2 * jj + 1];
                unsigned short h0 = f2bf(x0), h1 = f2bf(x1);
                unsigned short l0 = f2bf(x0 - bf2f(h0)), l1 = f2bf(x1 - bf2f(h1));
                wh[jj] = (unsigned)h0 | ((unsigned)h1 << 16);
                wl[jj] = (unsigned)l0 | ((unsigned)l1 << 16);
            }
            const int off = (((bb*128 + tl)*4 + dc)*64 + 32*hp + r32)*8;
            *reinterpret_cast<uint4*>(Khi + off) = make_uint4(wh[0], wh[1], wh[2], wh[3]);
            *reinterpret_cast<uint4*>(Klo + off) = make_uint4(wl[0], wl[1], wl[2], wl[3]);
        }
    }
}

// ---------------- flash attention: 4-wave blocks, LDS-shared K/V ----------
// grid (64 q-blocks, 8 key-splits), block 256 (4 waves). Wave w owns queries
// [bx*128 + w*32, +32); block iterates 8 x 64-key tiles of its 512-key range.
// LDS: staging S (48 KB) with sO (34.8 KB) aliased on top -> 3 blocks/CU.

__global__ __launch_bounds__(256, 3) void attn_kernel(
    const unsigned short* __restrict__ Qhi, const unsigned short* __restrict__ Qlo,
    const unsigned short* __restrict__ Khi, const unsigned short* __restrict__ Klo,
    const unsigned short* __restrict__ VT,
    float* __restrict__ Opart, float* __restrict__ ml)
{
    __shared__ unsigned char RAW[49152];
    auto S  = reinterpret_cast<unsigned short(*)[3][4096]>(RAW);  // 48 KB
    auto sO = reinterpret_cast<float(*)[32][68]>(RAW);            // 34.8 KB alias

    const int tid = threadIdx.x;
    const int w = tid >> 6;               // 0..3
    const int l = tid & 63;
    const int h = l >> 5;
    const int q = l & 31;
    const int bx = blockIdx.x;            // 0..63 q-block
    const int b  = bx >> 5;
    const int ks = blockIdx.y;            // 0..7 key-split
    const int rowg0 = bx * 128 + w * 32;  // wave's first global query row

    Frag qh[4], ql[4];
#pragma unroll
    for (int dc = 0; dc < 4; ++dc) {
        const int o = (rowg0 + q) * 64 + dc * 16 + 8 * h;
        qh[dc].i4 = *reinterpret_cast<const v4i*>(Qhi + o);
        ql[dc].i4 = *reinterpret_cast<const v4i*>(Qlo + o);
    }

    f32x16 o0, o1;
#pragma unroll
    for (int r = 0; r < 16; ++r) { o0[r] = 0.f; o1[r] = 0.f; }
    float m_run = -1e30f, l_run = 0.f;

    const size_t tb0 = ((size_t)(b * 128 + ks * 16)) * 2048;

    uint4 rgA0, rgA1, rgB0, rgB1, rgC0, rgC1;
    {   // prologue: stage tile-pair 0 (each thread: 2 uint4 per array)
        const size_t s = tb0 + (size_t)tid * 8;
        rgA0 = *reinterpret_cast<const uint4*>(Khi + s);
        rgA1 = *reinterpret_cast<const uint4*>(Khi + s + 2048);
        rgB0 = *reinterpret_cast<const uint4*>(Klo + s);
        rgB1 = *reinterpret_cast<const uint4*>(Klo + s + 2048);
        rgC0 = *reinterpret_cast<const uint4*>(VT + s);
        rgC1 = *reinterpret_cast<const uint4*>(VT + s + 2048);
        *reinterpret_cast<uint4*>(&S[0][0][tid * 8])        = rgA0;
        *reinterpret_cast<uint4*>(&S[0][0][tid * 8 + 2048]) = rgA1;
        *reinterpret_cast<uint4*>(&S[0][1][tid * 8])        = rgB0;
        *reinterpret_cast<uint4*>(&S[0][1][tid * 8 + 2048]) = rgB1;
        *reinterpret_cast<uint4*>(&S[0][2][tid * 8])        = rgC0;
        *reinterpret_cast<uint4*>(&S[0][2][tid * 8 + 2048]) = rgC1;
    }
    __syncthreads();

    for (int it = 0; it < 8; ++it) {
        const int cur = it & 1;
        if (it < 7) {   // issue next tile-pair's loads early (T14)
            const size_t s = tb0 + (size_t)(it + 1) * 4096 + (size_t)tid * 8;
            rgA0 = *reinterpret_cast<const uint4*>(Khi + s);
            rgA1 = *reinterpret_cast<const uint4*>(Khi + s + 2048);
            rgB0 = *reinterpret_cast<const uint4*>(Klo + s);
            rgB1 = *reinterpret_cast<const uint4*>(Klo + s + 2048);
            rgC0 = *reinterpret_cast<const uint4*>(VT + s);
            rgC1 = *reinterpret_cast<const uint4*>(VT + s + 2048);
        }

        // --- two independent score chains (sub-tiles A,B = 32 keys each)
        f32x16 sA, sB;
#pragma unroll
        for (int r = 0; r < 16; ++r) { sA[r] = 0.f; sB[r] = 0.f; }
#pragma unroll
        for (int dc = 0; dc < 4; ++dc) {
            Frag kha, kla, khb, klb;
            kha.i4 = *reinterpret_cast<const v4i*>(&S[cur][0][dc * 512 + l * 8]);
            khb.i4 = *reinterpret_cast<const v4i*>(&S[cur][0][2048 + dc * 512 + l * 8]);
            kla.i4 = *reinterpret_cast<const v4i*>(&S[cur][1][dc * 512 + l * 8]);
            klb.i4 = *reinterpret_cast<const v4i*>(&S[cur][1][2048 + dc * 512 + l * 8]);
            sA = MFMA32(kha.b8, qh[dc].b8, sA);
            sB = MFMA32(khb.b8, qh[dc].b8, sB);
            sA = MFMA32(kha.b8, ql[dc].b8, sA);
            sB = MFMA32(khb.b8, ql[dc].b8, sB);
            sA = MFMA32(kla.b8, qh[dc].b8, sA);
            sB = MFMA32(klb.b8, qh[dc].b8, sB);
        }

        // --- tile max (tree) + cross-half
        float mb;
        {
            float t[8];
#pragma unroll
            for (int jj = 0; jj < 4; ++jj) {
                t[jj]     = fmaxf(fmaxf(sA[4 * jj], sA[4 * jj + 1]),
                                  fmaxf(sA[4 * jj + 2], sA[4 * jj + 3]));
                t[4 + jj] = fmaxf(fmaxf(sB[4 * jj], sB[4 * jj + 1]),
                                  fmaxf(sB[4 * jj + 2], sB[4 * jj + 3]));
            }
            float u0 = fmaxf(fmaxf(t[0], t[1]), fmaxf(t[2], t[3]));
            float u1 = fmaxf(fmaxf(t[4], t[5]), fmaxf(t[6], t[7]));
            mb = fmaxf(u0, u1);
        }
        mb = fmaxf(mb, __shfl_xor(mb, 32));

        // --- defer-max (THR = 8)
        if (!__all(mb <= m_run + 8.f)) {
            const float m_new = fmaxf(m_run, mb);
            const float f = exp2f(m_run - m_new);
#pragma unroll
            for (int r = 0; r < 16; ++r) { o0[r] *= f; o1[r] *= f; }
            l_run *= f;
            m_run = m_new;
        }

        float p[32];
        float ps0 = 0.f, ps1 = 0.f, ps2 = 0.f, ps3 = 0.f;
#pragma unroll
        for (int r = 0; r < 16; r += 4) {
            p[r]      = exp2f(sA[r]     - m_run); ps0 += p[r];
            p[r + 1]  = exp2f(sA[r + 1] - m_run); ps1 += p[r + 1];
            p[r + 2]  = exp2f(sA[r + 2] - m_run); ps2 += p[r + 2];
            p[r + 3]  = exp2f(sA[r + 3] - m_run); ps3 += p[r + 3];
            p[16 + r]     = exp2f(sB[r]     - m_run); ps0 += p[16 + r];
            p[16 + r + 1] = exp2f(sB[r + 1] - m_run); ps1 += p[16 + r + 1];
            p[16 + r + 2] = exp2f(sB[r + 2] - m_run); ps2 += p[16 + r + 2];
            p[16 + r + 3] = exp2f(sB[r + 3] - m_run); ps3 += p[16 + r + 3];
        }
        float ps = (ps0 + ps1) + (ps2 + ps3);
        ps += __shfl_xor(ps, 32);
        l_run += ps;

        // --- P (C layout, k = (r&3)+8*(r>>2)+4h) -> bf16 B-frags, per tile
        unsigned U[16];
#pragma unroll
        for (int j = 0; j < 8; ++j) {
            U[j]     = cvt_pk_bf16(p[2 * j],      p[2 * j + 1]);
            U[8 + j] = cvt_pk_bf16(p[16 + 2 * j], p[16 + 2 * j + 1]);
        }
        unsigned tA0 = h ? U[0]  : U[2];
        unsigned tA1 = h ? U[1]  : U[3];
        unsigned tA2 = h ? U[4]  : U[6];
        unsigned tA3 = h ? U[5]  : U[7];
        unsigned tB0 = h ? U[8]  : U[10];
        unsigned tB1 = h ? U[9]  : U[11];
        unsigned tB2 = h ? U[12] : U[14];
        unsigned tB3 = h ? U[13] : U[15];
        unsigned rA0 = __shfl_xor(tA0, 32);
        unsigned rA1 = __shfl_xor(tA1, 32);
        unsigned rA2 = __shfl_xor(tA2, 32);
        unsigned rA3 = __shfl_xor(tA3, 32);
        unsigned rB0 = __shfl_xor(tB0, 32);
        unsigned rB1 = __shfl_xor(tB1, 32);
        unsigned rB2 = __shfl_xor(tB2, 32);
        unsigned rB3 = __shfl_xor(tB3, 32);
        Frag p0f, p1f, p2f, p3f;
        if (h == 0) {
            p0f.u[0] = U[0];  p0f.u[1] = U[1];  p0f.u[2] = rA0;   p0f.u[3] = rA1;
            p1f.u[0] = U[4];  p1f.u[1] = U[5];  p1f.u[2] = rA2;   p1f.u[3] = rA3;
            p2f.u[0] = U[8];  p2f.u[1] = U[9];  p2f.u[2] = rB0;   p2f.u[3] = rB1;
            p3f.u[0] = U[12]; p3f.u[1] = U[13]; p3f.u[2] = rB2;   p3f.u[3] = rB3;
        } else {
            p0f.u[0] = rA0;   p0f.u[1] = rA1;   p0f.u[2] = U[2];  p0f.u[3] = U[3];
            p1f.u[0] = rA2;   p1f.u[1] = rA3;   p1f.u[2] = U[6];  p1f.u[3] = U[7];
            p2f.u[0] = rB0;   p2f.u[1] = rB1;   p2f.u[2] = U[10]; p2f.u[3] = U[11];
            p3f.u[0] = rB2;   p3f.u[1] = rB3;   p3f.u[2] = U[14]; p3f.u[3] = U[15];
        }

        // --- PV from LDS V tiles
#pragma unroll
        for (int tb = 0; tb < 2; ++tb) {
#pragma unroll
            for (int c = 0; c < 2; ++c) {
                const Frag& pf = tb ? (c ? p3f : p2f) : (c ? p1f : p0f);
#pragma unroll
                for (int vc = 0; vc < 2; ++vc) {
                    Frag vf;
                    vf.i4 = *reinterpret_cast<const v4i*>(
                        &S[cur][2][tb * 2048 + (c * 2 + vc) * 512 + l * 8]);
                    if (vc == 0) o0 = MFMA32(vf.b8, pf.b8, o0);
                    else         o1 = MFMA32(vf.b8, pf.b8, o1);
                }
            }
        }

        if (it < 7) {   // write next tile-pair into the other buffer
            const int nxt = cur ^ 1;
            *reinterpret_cast<uint4*>(&S[nxt][0][tid * 8])        = rgA0;
            *reinterpret_cast<uint4*>(&S[nxt][0][tid * 8 + 2048]) = rgA1;
            *reinterpret_cast<uint4*>(&S[nxt][1][tid * 8])        = rgB0;
            *reinterpret_cast<uint4*>(&S[nxt][1][tid * 8 + 2048]) = rgB1;
            *reinterpret_cast<uint4*>(&S[nxt][2][tid * 8])        = rgC0;
            *reinterpret_cast<uint4*>(&S[nxt][2][tid * 8 + 2048]) = rgC1;
        }
        __syncthreads();   // also fences the last S read before sO reuse
    }

    // --- epilogue: per-wave (m,l) + O transpose through LDS (aliased), store
    if (h == 0) {
        const int rowg = rowg0 + q;
        *reinterpret_cast<float2*>(&ml[((size_t)ks * 8192 + rowg) * 2]) =
            make_float2(m_run, l_run);
    }
#pragma unroll
    for (int vc = 0; vc < 2; ++vc) {
        const f32x16& a = vc ? o1 : o0;
#pragma unroll
        for (int u = 0; u < 4; ++u) {
            float4 v4 = make_float4(a[4 * u], a[4 * u + 1], a[4 * u + 2], a[4 * u + 3]);
            *reinterpret_cast<float4*>(&sO[w][q][vc * 32 + 8 * u + 4 * h]) = v4;
        }
    }
    __syncthreads();

#pragma unroll
    for (int k = 0; k < 8; ++k) {
        const int f = tid + k * 256;          // 2048 float4 slots (128 rows x 16)
        const int rl = f >> 4;                // local row 0..127
        const int v4 = f & 15;
        float4 val = *reinterpret_cast<const float4*>(&sO[rl >> 5][rl & 31][v4 * 4]);
        *reinterpret_cast<float4*>(
            &Opart[(((size_t)ks * 8192) + bx * 128 + rl) * 64 + v4 * 4]) = val;
    }
}

// ---------------- 8-way cross-split merge (verbatim R12) ----------------
__global__ __launch_bounds__(256) void merge_kernel(
    const float* __restrict__ Opart, const float* __restrict__ ml, float* __restrict__ out)
{
    const int idx = blockIdx.x * 256 + threadIdx.x;  // 131072
    const int row = idx >> 4, vb = (idx & 15) * 4;
    float mv[8], lv[8];
    float ms = -1e30f;
#pragma unroll
    for (int s = 0; s < 8; ++s) {
        float2 m2 = *reinterpret_cast<const float2*>(&ml[((size_t)s * 8192 + row) * 2]);
        mv[s] = m2.x; lv[s] = m2.y;
        ms = fmaxf(ms, m2.x);
    }
    float L = 0.f;
    float a0 = 0.f, a1 = 0.f, a2 = 0.f, a3 = 0.f;
#pragma unroll
    for (int s = 0; s < 8; ++s) {
        const float fw = exp2f(mv[s] - ms);
        L += fw * lv[s];
        float4 a = *reinterpret_cast<const float4*>(
            &Opart[((size_t)s * 8192 + row) * 64 + vb]);
        a0 += fw * a.x; a1 += fw * a.y; a2 += fw * a.z; a3 += fw * a.w;
    }
    const float inv = 1.0f / L;
    *reinterpret_cast<float4*>(out + (size_t)row * 64 + vb) =
        make_float4(a0 * inv, a1 * inv, a2 * inv, a3 * inv);
}

// ---------------- launch ----------------

extern "C" void kernel_launch(void* const* d_in, const int* in_sizes, int n_in,
                              void* d_out, int out_size, void* d_ws, size_t ws_size,
                              hipStream_t stream)
{
    const float* X  = (const float*)d_in[0];
    const float* Wq = (const float*)d_in[1];
    const float* Wk = (const float*)d_in[2];
    const float* Wv = (const float*)d_in[3];
    float* out = (float*)d_out;

    // workspace: QKV-packed buffers first; W (proj-time only) aliased by
    // Opart/ml (written only by attn/merge). ~21.5 MiB.
    unsigned short* Qhi = (unsigned short*)d_ws;
    unsigned short* Qlo = Qhi + 524288;    // 8192*64
    unsigned short* Khi = Qlo + 524288;    // Kpk hi: [2][128][4][64][8]
    unsigned short* Klo = Khi + 524288;    // Kpk lo
    unsigned short* VT  = Klo + 524288;    // Vpk: [2][128][2][2][64][8]
    unsigned short* Whi = VT + 524288;     // 192*512 (proj-time only)
    unsigned short* Wlo = Whi + 98304;
    float* Opart = (float*)Whi;            // [8][8192][64] fp32 (aliases W)
    float* ml    = Opart + 4194304;        // [8][8192][2]

    splitW_kernel<<<96, 256, 0, stream>>>(Wq, Wk, Wv, Whi, Wlo);
    proj_kernel<<<256, 384, 0, stream>>>(X, Whi, Wlo, Qhi, Qlo, Khi, Klo, VT);
    attn_kernel<<<dim3(64, 8), 256, 0, stream>>>(Qhi, Qlo, Khi, Klo, VT, Opart, ml);
    merge_kernel<<<512, 256, 0, stream>>>(Opart, ml, out);
}